// Round 10
// baseline (159.380 us; speedup 1.0000x reference)
//
#include <hip/hip_runtime.h>

#define EPS 1e-7f
#define T_DIM 2048
#define TP1   2049
#define H_DIM 8
#define B_DIM 8

#define NFRAG 146          // fb_phys in [0,146): b0 = fbp*16 - 160 (first 8 entries all-zero pad)
#define NST   33           // 64-wide s-tiles per b (covers s in [0,2112), zero past 2048)
#define RSTRIDE 66         // post-loop LDS reduction row stride

#define J1_BLOCKS 292      // 8*146*64/256 fragA entries
#define J2_BLOCKS 264      // 8 b * 33 st transpose tiles
#define J3_BLOCKS 4098     // head-H rows: 8*2049/4
#define MM_BLOCKS 1088     // 17 t0-levels * 8 b * 8 heads

typedef short v8s __attribute__((ext_vector_type(8)));
typedef float v4f __attribute__((ext_vector_type(4)));

static __device__ __forceinline__ unsigned short f2bf(float f) {
  union { float f; unsigned u; } v; v.f = f;
  unsigned r = v.u + 0x7fffu + ((v.u >> 16) & 1u);  // RTNE
  return (unsigned short)(r >> 16);
}

// prep: [J1] MFMA A-fragment table, [J2] x -> bf16 transpose into swizzled 8KB
// chunks xT[b][st][dd][slot^(dd&7)][8], [J3] head-H l2norm output.
__global__ __launch_bounds__(256) void prep(const float* __restrict__ x,
                                            const float* __restrict__ W,
                                            unsigned short* __restrict__ fragA,
                                            unsigned short* __restrict__ xT,
                                            float* __restrict__ out) {
  __shared__ float tile[64][65];
  int bid = blockIdx.x;
  if (bid < J1_BLOCKS) {
    // fragA[((h*NFRAG+fbp)*64+lane)*8]: A[m=lm][k=8q+j] = k_h[b0+lm-8q-j], b0=fbp*16-160
    int tid = bid * 256 + threadIdx.x;
    int blk = tid >> 6, lane = tid & 63;
    int h = blk / NFRAG, fbp = blk - h * NFRAG;
    int b0 = fbp * 16 - 160;
    int lm = lane & 15, quad = lane >> 4;
    v8s frag;
    #pragma unroll
    for (int j = 0; j < 8; ++j) {
      int d = b0 + lm - 8 * quad - j;
      float v = 0.0f;
      if (d >= 0 && d < T_DIM) v = __expf(W[d * H_DIM + h]);
      else if (d == T_DIM) v = 1.0f;
      frag[j] = (short)f2bf(v);
    }
    *(v8s*)(fragA + (size_t)tid * 8) = frag;
    return;
  }
  bid -= J1_BLOCKS;
  if (bid < J2_BLOCKS) {
    int b = bid / NST, st = bid - b * NST;
    int s0 = st * 64;
    int tid = threadIdx.x;
    int c = tid & 63, r4 = tid >> 6;
    #pragma unroll
    for (int i = 0; i < 16; ++i) {
      int sl = r4 * 16 + i;
      int s = s0 + sl;
      tile[sl][c] = (s < T_DIM) ? x[((size_t)b * T_DIM + s) * 64 + c] : 0.0f;
    }
    __syncthreads();
    // chunk byte layout: dd*128 + p*16 + j*2 holds s_local = (p^(dd&7))*8 + j
    int dd = tid >> 2, pb = (tid & 3) * 2;
    unsigned short* dst = xT + ((size_t)(b * NST + st) << 12) + dd * 64;
    #pragma unroll
    for (int e = 0; e < 2; ++e) {
      int p = pb + e;
      int sb = ((p ^ (dd & 7)) << 3);
      v8s o;
      #pragma unroll
      for (int j = 0; j < 8; ++j) o[j] = (short)f2bf(tile[sb + j][dd]);
      *(v8s*)(dst + p * 8) = o;
    }
    return;
  }
  bid -= J2_BLOCKS;
  {  // head H: single l2norm of xp
    int row = bid * 4 + (threadIdx.x >> 6);
    if (row >= B_DIM * TP1) return;
    int b = row / TP1, t = row - b * TP1;
    int dd = threadIdx.x & 63;
    float v = (t < T_DIM) ? x[((size_t)b * T_DIM + t) * 64 + dd] : 0.0f;
    float ss = v * v;
    ss += __shfl_xor(ss, 1);  ss += __shfl_xor(ss, 2);
    ss += __shfl_xor(ss, 4);  ss += __shfl_xor(ss, 8);
    ss += __shfl_xor(ss, 16); ss += __shfl_xor(ss, 32);
    float inv = 1.0f / (sqrtf(ss) + EPS);
    __builtin_nontemporal_store(v * inv,
        &out[(((size_t)(H_DIM * B_DIM + b) * TP1 + t) << 6) + dd]);
  }
}

// DIRECT-TO-REGISTER MM (R8 probe: the LDS-staging skeleton alone cost 37%
// of the kernel and serialized additively with compute; R2-R7 proved no
// schedule inside that skeleton helps). Structure = R0's proven zero-barrier
// register-pipelined loop + the swizzled-chunk xT layout (fixes R0's B-read
// line waste: every load is a dense coalesced 16B/lane read inside an 8KB
// chunk). Block = (h, ONE b, 128 rows), 4 waves: wm row-half, wk K-split;
// per wave chunks c0 = 64*it + 32*wk, 2-deep a/b register rotation, ~8 KB
// in flight per wave, 16 independent waves/CU (4.25 blocks/CU) -- latency
// hidden by TLP, zero main-loop barriers/LDS.
// A-entry direct index: fbp = (tw - c0 + 160)>>4 + mt (== staged-window
// algebra E0p + 2 + 4wm - 2wk + mt; range 8..141, in-table).
// B swizzle (BUGFIX vs R9): koff = (c0>>5)&1 == wk (constant), and it lives
// INSIDE the p-slot XOR: byte = nt*2048 + lm*128 + ((((wk<<2)|quad)^(lm&7))<<4)
// -- NOT koff*1024 (that jumps 8 dd-rows; wk=1 waves read garbage).
// K-split reduction + double-l2norm epilogue (R5-proven, only __syncthreads).
// h = bid&7 pins one head per XCD.
__global__ __launch_bounds__(256, 4) void toeplitz_mm(const unsigned short* __restrict__ fragA,
                                                      const unsigned short* __restrict__ xT,
                                                      float* __restrict__ out) {
  __shared__ float red[2][64 * RSTRIDE];   // 33.8 KB

  const int lane = threadIdx.x & 63;
  const int w    = threadIdx.x >> 6;
  const int wm   = w & 1;
  const int wk   = w >> 1;
  const int lm   = lane & 15;
  const int quad = lane >> 4;

  const int bid = blockIdx.x;
  const int h   = bid & 7;
  const int b   = (bid >> 3) & 7;
  const int k   = bid >> 6;                 // 0..16
  const int lvl = (k < 4) ? 2 * k : (k < 12) ? 23 - 2 * k : (k < 16) ? 2 * k - 16 : 16;
  const int t0  = T_DIM - lvl * 128;
  const int tw  = t0 + 64 * wm;
  const bool active = (tw <= T_DIM);
  const int cap = min(tw + 32, T_DIM);      // last valid 32-chunk base for this wave

  const unsigned short* fA = fragA + ((size_t)h * NFRAG) * 512 + lane * 8;
  // per-thread constant swizzle: koff == wk for every chunk this wave touches
  const int swz = lm * 128 + ((((wk << 2) | quad) ^ (lm & 7)) << 4);

  // A: af[mt] = entry (tw - c0 + 160)>>4 + mt (1KB entries; 16B/lane)
#define LOAD_A(dst, c0v) do {                                                  \
    const unsigned short* _p = fA + (size_t)((tw - (c0v) + 160) >> 4) * 512;   \
    dst[0] = *(const v8s*)(_p);                                                \
    dst[1] = *(const v8s*)(_p + 512);                                          \
    dst[2] = *(const v8s*)(_p + 1024);                                         \
    dst[3] = *(const v8s*)(_p + 1536); } while (0)
  // B: chunk (b, st = c0>>6); within-chunk byte = nt*2048 + swz
#define LOAD_B(dst, c0v) do {                                                  \
    const char* _cb = (const char*)(xT + ((size_t)(b * NST + ((c0v) >> 6)) << 12)) + swz; \
    dst[0] = *(const v8s*)(_cb);                                               \
    dst[1] = *(const v8s*)(_cb + 2048);                                        \
    dst[2] = *(const v8s*)(_cb + 4096);                                        \
    dst[3] = *(const v8s*)(_cb + 6144); } while (0)
#define DO_MFMA(fa, fb) do {                                                   \
    _Pragma("unroll")                                                          \
    for (int mt = 0; mt < 4; ++mt)                                             \
      _Pragma("unroll")                                                        \
      for (int nt = 0; nt < 4; ++nt)                                           \
        acc[mt][nt] = __builtin_amdgcn_mfma_f32_16x16x32_bf16(fa[mt], fb[nt],  \
                                                              acc[mt][nt], 0, 0, 0); } while (0)

  v4f acc[4][4] = {};  // rows tw+16*mt+4*quad+r, cols 16*nt+lm; this wave's wk half of K

  if (active) {
    v8s a0[4], a1[4], b0[4], b1[4];
    int c0 = 32 * wk;
    LOAD_A(a0, c0); LOAD_B(b0, c0);
    for (;;) {
      bool more = (c0 + 64 <= cap);
      if (more) { LOAD_A(a1, c0 + 64); LOAD_B(b1, c0 + 64); }
      DO_MFMA(a0, b0);
      if (!more) break;
      c0 += 64;
      bool more2 = (c0 + 64 <= cap);
      if (more2) { LOAD_A(a0, c0 + 64); LOAD_B(b0, c0 + 64); }
      DO_MFMA(a1, b1);
      if (!more2) break;
      c0 += 64;
    }
  }

  // K-split reduction in LDS: wk=1 dumps partials; wk=0 reduces + epilogue.
  float* bufp = red[wm];
  if (wk == 1) {
    #pragma unroll
    for (int mt = 0; mt < 4; ++mt)
      #pragma unroll
      for (int r = 0; r < 4; ++r) {
        int row = 16 * mt + 4 * quad + r;
        #pragma unroll
        for (int nt = 0; nt < 4; ++nt)
          bufp[row * RSTRIDE + 16 * nt + lm] = acc[mt][nt][r];
      }
  }
  __syncthreads();
  if (wk != 0) return;

  #pragma unroll
  for (int mt = 0; mt < 4; ++mt) {
    #pragma unroll
    for (int r = 0; r < 4; ++r) {
      int row = 16 * mt + 4 * quad + r;
      #pragma unroll
      for (int nt = 0; nt < 4; ++nt)
        acc[mt][nt][r] += bufp[row * RSTRIDE + 16 * nt + lm];
    }
  }

  if (!active) return;

  // Epilogue: double l2-norm over dd (softmax Z cancels up to eps ~3e-7).
  // C/D layout: col = lane&15 (dd offset), row = quad*4 + reg.
  #pragma unroll
  for (int mt = 0; mt < 4; ++mt) {
    #pragma unroll
    for (int r = 0; r < 4; ++r) {
      float ss = 0.0f;
      #pragma unroll
      for (int nt = 0; nt < 4; ++nt) { float a = acc[mt][nt][r]; ss += a * a; }
      ss += __shfl_xor(ss, 1);
      ss += __shfl_xor(ss, 2);
      ss += __shfl_xor(ss, 4);
      ss += __shfl_xor(ss, 8);
      int t = tw + 16 * mt + 4 * quad + r;
      if (t <= T_DIM) {
        float n1 = sqrtf(ss);
        float u  = n1 / (n1 + EPS);
        float inv = 1.0f / ((n1 + EPS) * (u + EPS));
        float* op = out + (((size_t)(h * B_DIM + b) * TP1 + t) << 6) + lm;
        #pragma unroll
        for (int nt = 0; nt < 4; ++nt)
          __builtin_nontemporal_store(acc[mt][nt][r] * inv, op + 16 * nt);
      }
    }
  }
#undef LOAD_A
#undef LOAD_B
#undef DO_MFMA
}

extern "C" void kernel_launch(void* const* d_in, const int* in_sizes, int n_in,
                              void* d_out, int out_size, void* d_ws, size_t ws_size,
                              hipStream_t stream) {
  const float* x = (const float*)d_in[0];   // [8, 2048, 64] fp32
  const float* W = (const float*)d_in[1];   // [2048, 8] fp32
  float* out = (float*)d_out;               // [9, 8, 2049, 64] fp32

  unsigned short* xT    = (unsigned short*)d_ws;                    // 8*33*8192 = 2,162,688 B
  unsigned short* fragA = (unsigned short*)((char*)d_ws + 2162688); // 8*146*1024 = 1,196,032 B

  hipLaunchKernelGGL(prep, dim3(J1_BLOCKS + J2_BLOCKS + J3_BLOCKS), dim3(256), 0, stream,
                     x, W, fragA, xT, out);
  hipLaunchKernelGGL(toeplitz_mm, dim3(MM_BLOCKS), dim3(256), 0, stream,
                     fragA, xT, out);
}

// Round 11
// 112.904 us; speedup vs baseline: 1.4116x; 1.4116x over previous
//
#include <hip/hip_runtime.h>

#define EPS 1e-7f
#define T_DIM 2048
#define TP1   2049
#define H_DIM 8
#define B_DIM 8

#define NFRAG 146          // fb_phys in [0,146): b0 = fbp*16 - 160 (first 8 entries all-zero pad)
#define NST   33           // 64-wide s-tiles per b (covers s in [0,2112), zero past 2048)
#define RSTRIDE 66         // post-loop LDS reduction row stride

#define J1_BLOCKS 292      // 8*146*64/256 fragA entries
#define J2_BLOCKS 264      // 8 b * 33 st transpose tiles
#define J3_BLOCKS 4098     // head-H rows: 8*2049/4
#define MM_BLOCKS 1088     // 17 t0-levels * 8 b * 8 heads

typedef short v8s __attribute__((ext_vector_type(8)));
typedef float v4f __attribute__((ext_vector_type(4)));

static __device__ __forceinline__ unsigned short f2bf(float f) {
  union { float f; unsigned u; } v; v.f = f;
  unsigned r = v.u + 0x7fffu + ((v.u >> 16) & 1u);  // RTNE
  return (unsigned short)(r >> 16);
}

// prep: [J1] MFMA A-fragment table, [J2] x -> bf16 transpose into swizzled 8KB
// chunks xT[b][st][dd][slot^(dd&7)][8], [J3] head-H l2norm output.
__global__ __launch_bounds__(256) void prep(const float* __restrict__ x,
                                            const float* __restrict__ W,
                                            unsigned short* __restrict__ fragA,
                                            unsigned short* __restrict__ xT,
                                            float* __restrict__ out) {
  __shared__ float tile[64][65];
  int bid = blockIdx.x;
  if (bid < J1_BLOCKS) {
    // fragA[((h*NFRAG+fbp)*64+lane)*8]: A[m=lm][k=8q+j] = k_h[b0+lm-8q-j], b0=fbp*16-160
    int tid = bid * 256 + threadIdx.x;
    int blk = tid >> 6, lane = tid & 63;
    int h = blk / NFRAG, fbp = blk - h * NFRAG;
    int b0 = fbp * 16 - 160;
    int lm = lane & 15, quad = lane >> 4;
    v8s frag;
    #pragma unroll
    for (int j = 0; j < 8; ++j) {
      int d = b0 + lm - 8 * quad - j;
      float v = 0.0f;
      if (d >= 0 && d < T_DIM) v = __expf(W[d * H_DIM + h]);
      else if (d == T_DIM) v = 1.0f;
      frag[j] = (short)f2bf(v);
    }
    *(v8s*)(fragA + (size_t)tid * 8) = frag;
    return;
  }
  bid -= J1_BLOCKS;
  if (bid < J2_BLOCKS) {
    int b = bid / NST, st = bid - b * NST;
    int s0 = st * 64;
    int tid = threadIdx.x;
    int c = tid & 63, r4 = tid >> 6;
    #pragma unroll
    for (int i = 0; i < 16; ++i) {
      int sl = r4 * 16 + i;
      int s = s0 + sl;
      tile[sl][c] = (s < T_DIM) ? x[((size_t)b * T_DIM + s) * 64 + c] : 0.0f;
    }
    __syncthreads();
    // chunk byte layout: dd*128 + p*16 + j*2 holds s_local = (p^(dd&7))*8 + j
    int dd = tid >> 2, pb = (tid & 3) * 2;
    unsigned short* dst = xT + ((size_t)(b * NST + st) << 12) + dd * 64;
    #pragma unroll
    for (int e = 0; e < 2; ++e) {
      int p = pb + e;
      int sb = ((p ^ (dd & 7)) << 3);
      v8s o;
      #pragma unroll
      for (int j = 0; j < 8; ++j) o[j] = (short)f2bf(tile[sb + j][dd]);
      *(v8s*)(dst + p * 8) = o;
    }
    return;
  }
  bid -= J2_BLOCKS;
  {  // head H: single l2norm of xp
    int row = bid * 4 + (threadIdx.x >> 6);
    if (row >= B_DIM * TP1) return;
    int b = row / TP1, t = row - b * TP1;
    int dd = threadIdx.x & 63;
    float v = (t < T_DIM) ? x[((size_t)b * T_DIM + t) * 64 + dd] : 0.0f;
    float ss = v * v;
    ss += __shfl_xor(ss, 1);  ss += __shfl_xor(ss, 2);
    ss += __shfl_xor(ss, 4);  ss += __shfl_xor(ss, 8);
    ss += __shfl_xor(ss, 16); ss += __shfl_xor(ss, 32);
    float inv = 1.0f / (sqrtf(ss) + EPS);
    __builtin_nontemporal_store(v * inv,
        &out[(((size_t)(H_DIM * B_DIM + b) * TP1 + t) << 6) + dd]);
  }
}

// DIRECT-TO-REGISTER MM (R8 probe: the LDS-staging skeleton alone cost 37%
// of the kernel and serialized additively with compute). Structure = R0's
// proven zero-barrier register-pipelined loop + the swizzled-chunk xT layout
// (every B load = dense coalesced 16B/lane read inside an 8KB chunk;
// correctness verified R10). Block = (h, ONE b, 128 rows), 4 waves: wm
// row-half, wk K-split; 2-deep a/b register rotation, zero main-loop
// barriers/LDS; latency hidden by independent-wave TLP.
// LAUNCH BOUNDS (R10 post-mortem): plain (256) -- NO min-waves arg. R10's
// (256,4) capped VGPR and spilled the ~128-live-reg loop to scratch:
// VGPR_Count 64, WRITE_SIZE 142MB (vs 33MB output), 94us. R0 ran this
// register structure at VGPR=104, zero spill, with plain (256).
// A-entry: fbp = (tw - c0 + 160)>>4 + mt (range 8..141, in-table).
// B swizzle: koff == wk constant, inside the p-slot XOR:
// byte = nt*2048 + lm*128 + ((((wk<<2)|quad)^(lm&7))<<4).
// K-split reduction + double-l2norm epilogue. h = bid&7 pins head per XCD.
__global__ __launch_bounds__(256) void toeplitz_mm(const unsigned short* __restrict__ fragA,
                                                   const unsigned short* __restrict__ xT,
                                                   float* __restrict__ out) {
  __shared__ float red[2][64 * RSTRIDE];   // 33.8 KB

  const int lane = threadIdx.x & 63;
  const int w    = threadIdx.x >> 6;
  const int wm   = w & 1;
  const int wk   = w >> 1;
  const int lm   = lane & 15;
  const int quad = lane >> 4;

  const int bid = blockIdx.x;
  const int h   = bid & 7;
  const int b   = (bid >> 3) & 7;
  const int k   = bid >> 6;                 // 0..16
  const int lvl = (k < 4) ? 2 * k : (k < 12) ? 23 - 2 * k : (k < 16) ? 2 * k - 16 : 16;
  const int t0  = T_DIM - lvl * 128;
  const int tw  = t0 + 64 * wm;
  const bool active = (tw <= T_DIM);
  const int cap = min(tw + 32, T_DIM);      // last valid 32-chunk base for this wave

  const unsigned short* fA = fragA + ((size_t)h * NFRAG) * 512 + lane * 8;
  // per-thread constant swizzle: koff == wk for every chunk this wave touches
  const int swz = lm * 128 + ((((wk << 2) | quad) ^ (lm & 7)) << 4);

  // A: af[mt] = entry (tw - c0 + 160)>>4 + mt (1KB entries; 16B/lane)
#define LOAD_A(dst, c0v) do {                                                  \
    const unsigned short* _p = fA + (size_t)((tw - (c0v) + 160) >> 4) * 512;   \
    dst[0] = *(const v8s*)(_p);                                                \
    dst[1] = *(const v8s*)(_p + 512);                                          \
    dst[2] = *(const v8s*)(_p + 1024);                                         \
    dst[3] = *(const v8s*)(_p + 1536); } while (0)
  // B: chunk (b, st = c0>>6); within-chunk byte = nt*2048 + swz
#define LOAD_B(dst, c0v) do {                                                  \
    const char* _cb = (const char*)(xT + ((size_t)(b * NST + ((c0v) >> 6)) << 12)) + swz; \
    dst[0] = *(const v8s*)(_cb);                                               \
    dst[1] = *(const v8s*)(_cb + 2048);                                        \
    dst[2] = *(const v8s*)(_cb + 4096);                                        \
    dst[3] = *(const v8s*)(_cb + 6144); } while (0)
#define DO_MFMA(fa, fb) do {                                                   \
    _Pragma("unroll")                                                          \
    for (int mt = 0; mt < 4; ++mt)                                             \
      _Pragma("unroll")                                                        \
      for (int nt = 0; nt < 4; ++nt)                                           \
        acc[mt][nt] = __builtin_amdgcn_mfma_f32_16x16x32_bf16(fa[mt], fb[nt],  \
                                                              acc[mt][nt], 0, 0, 0); } while (0)

  v4f acc[4][4] = {};  // rows tw+16*mt+4*quad+r, cols 16*nt+lm; this wave's wk half of K

  if (active) {
    v8s a0[4], a1[4], b0[4], b1[4];
    int c0 = 32 * wk;
    LOAD_A(a0, c0); LOAD_B(b0, c0);
    for (;;) {
      bool more = (c0 + 64 <= cap);
      if (more) { LOAD_A(a1, c0 + 64); LOAD_B(b1, c0 + 64); }
      DO_MFMA(a0, b0);
      if (!more) break;
      c0 += 64;
      bool more2 = (c0 + 64 <= cap);
      if (more2) { LOAD_A(a0, c0 + 64); LOAD_B(b0, c0 + 64); }
      DO_MFMA(a1, b1);
      if (!more2) break;
      c0 += 64;
    }
  }

  // K-split reduction in LDS: wk=1 dumps partials; wk=0 reduces + epilogue.
  float* bufp = red[wm];
  if (wk == 1) {
    #pragma unroll
    for (int mt = 0; mt < 4; ++mt)
      #pragma unroll
      for (int r = 0; r < 4; ++r) {
        int row = 16 * mt + 4 * quad + r;
        #pragma unroll
        for (int nt = 0; nt < 4; ++nt)
          bufp[row * RSTRIDE + 16 * nt + lm] = acc[mt][nt][r];
      }
  }
  __syncthreads();
  if (wk != 0) return;

  #pragma unroll
  for (int mt = 0; mt < 4; ++mt) {
    #pragma unroll
    for (int r = 0; r < 4; ++r) {
      int row = 16 * mt + 4 * quad + r;
      #pragma unroll
      for (int nt = 0; nt < 4; ++nt)
        acc[mt][nt][r] += bufp[row * RSTRIDE + 16 * nt + lm];
    }
  }

  if (!active) return;

  // Epilogue: double l2-norm over dd (softmax Z cancels up to eps ~3e-7).
  // C/D layout: col = lane&15 (dd offset), row = quad*4 + reg.
  #pragma unroll
  for (int mt = 0; mt < 4; ++mt) {
    #pragma unroll
    for (int r = 0; r < 4; ++r) {
      float ss = 0.0f;
      #pragma unroll
      for (int nt = 0; nt < 4; ++nt) { float a = acc[mt][nt][r]; ss += a * a; }
      ss += __shfl_xor(ss, 1);
      ss += __shfl_xor(ss, 2);
      ss += __shfl_xor(ss, 4);
      ss += __shfl_xor(ss, 8);
      int t = tw + 16 * mt + 4 * quad + r;
      if (t <= T_DIM) {
        float n1 = sqrtf(ss);
        float u  = n1 / (n1 + EPS);
        float inv = 1.0f / ((n1 + EPS) * (u + EPS));
        float* op = out + (((size_t)(h * B_DIM + b) * TP1 + t) << 6) + lm;
        #pragma unroll
        for (int nt = 0; nt < 4; ++nt)
          __builtin_nontemporal_store(acc[mt][nt][r] * inv, op + 16 * nt);
      }
    }
  }
#undef LOAD_A
#undef LOAD_B
#undef DO_MFMA
}

extern "C" void kernel_launch(void* const* d_in, const int* in_sizes, int n_in,
                              void* d_out, int out_size, void* d_ws, size_t ws_size,
                              hipStream_t stream) {
  const float* x = (const float*)d_in[0];   // [8, 2048, 64] fp32
  const float* W = (const float*)d_in[1];   // [2048, 8] fp32
  float* out = (float*)d_out;               // [9, 8, 2049, 64] fp32

  unsigned short* xT    = (unsigned short*)d_ws;                    // 8*33*8192 = 2,162,688 B
  unsigned short* fragA = (unsigned short*)((char*)d_ws + 2162688); // 8*146*1024 = 1,196,032 B

  hipLaunchKernelGGL(prep, dim3(J1_BLOCKS + J2_BLOCKS + J3_BLOCKS), dim3(256), 0, stream,
                     x, W, fragA, xT, out);
  hipLaunchKernelGGL(toeplitz_mm, dim3(MM_BLOCKS), dim3(256), 0, stream,
                     fragA, xT, out);
}

// Round 12
// 101.197 us; speedup vs baseline: 1.5750x; 1.1157x over previous
//
#include <hip/hip_runtime.h>

#define EPS 1e-7f
#define T_DIM 2048
#define TP1   2049
#define H_DIM 8
#define B_DIM 8

#define NFRAG 146          // fb_phys in [0,146): b0 = fbp*16 - 160 (first 8 entries all-zero pad)
#define NST   33           // 64-wide s-tiles per b (covers s in [0,2112), zero past 2048)
#define AREG  10240        // A region bytes per LDS buffer (10 x 1KB entries)
#define BUFSZ 26624        // A 10KB + B 2 x 8KB

#define J1_BLOCKS 292      // 8*146*64/256 fragA entries
#define J2_BLOCKS 264      // 8 b * 33 st transpose tiles
#define J3_BLOCKS 1025     // head-H rows: 8*2049 / 16 rows per block
#define MM_BLOCKS 544      // 17 t0-levels * 4 b-groups * 8 heads

typedef short v8s __attribute__((ext_vector_type(8)));
typedef float v4f __attribute__((ext_vector_type(4)));

static __device__ __forceinline__ unsigned short f2bf(float f) {
  union { float f; unsigned u; } v; v.f = f;
  unsigned r = v.u + 0x7fffu + ((v.u >> 16) & 1u);  // RTNE
  return (unsigned short)(r >> 16);
}

static __device__ __forceinline__ void load_lds16(const void* g, void* l) {
  __builtin_amdgcn_global_load_lds(
      (const __attribute__((address_space(1))) unsigned int*)g,
      (__attribute__((address_space(3))) unsigned int*)l, 16, 0, 0);
}

// prep: [J1] MFMA A-fragment table, [J2] x -> bf16 transpose into swizzled 8KB
// chunks xT[b][st][dd][slot^(dd&7)][8], [J3] head-H l2norm (16 rows/block:
// 4 waves x 4 sequential rows -- 1025 blocks instead of 4098, J3 was
// dispatch-rate-limited).
__global__ __launch_bounds__(256) void prep(const float* __restrict__ x,
                                            const float* __restrict__ W,
                                            unsigned short* __restrict__ fragA,
                                            unsigned short* __restrict__ xT,
                                            float* __restrict__ out) {
  __shared__ float tile[64][65];
  int bid = blockIdx.x;
  if (bid < J1_BLOCKS) {
    // fragA[((h*NFRAG+fbp)*64+lane)*8]: A[m=lm][k=8q+j] = k_h[b0+lm-8q-j], b0=fbp*16-160
    int tid = bid * 256 + threadIdx.x;
    int blk = tid >> 6, lane = tid & 63;
    int h = blk / NFRAG, fbp = blk - h * NFRAG;
    int b0 = fbp * 16 - 160;
    int lm = lane & 15, quad = lane >> 4;
    v8s frag;
    #pragma unroll
    for (int j = 0; j < 8; ++j) {
      int d = b0 + lm - 8 * quad - j;
      float v = 0.0f;
      if (d >= 0 && d < T_DIM) v = __expf(W[d * H_DIM + h]);
      else if (d == T_DIM) v = 1.0f;
      frag[j] = (short)f2bf(v);
    }
    *(v8s*)(fragA + (size_t)tid * 8) = frag;
    return;
  }
  bid -= J1_BLOCKS;
  if (bid < J2_BLOCKS) {
    int b = bid / NST, st = bid - b * NST;
    int s0 = st * 64;
    int tid = threadIdx.x;
    int c = tid & 63, r4 = tid >> 6;
    #pragma unroll
    for (int i = 0; i < 16; ++i) {
      int sl = r4 * 16 + i;
      int s = s0 + sl;
      tile[sl][c] = (s < T_DIM) ? x[((size_t)b * T_DIM + s) * 64 + c] : 0.0f;
    }
    __syncthreads();
    // chunk byte layout: dd*128 + p*16 + j*2 holds s_local = (p^(dd&7))*8 + j
    int dd = tid >> 2, pb = (tid & 3) * 2;
    unsigned short* dst = xT + ((size_t)(b * NST + st) << 12) + dd * 64;
    #pragma unroll
    for (int e = 0; e < 2; ++e) {
      int p = pb + e;
      int sb = ((p ^ (dd & 7)) << 3);
      v8s o;
      #pragma unroll
      for (int j = 0; j < 8; ++j) o[j] = (short)f2bf(tile[sb + j][dd]);
      *(v8s*)(dst + p * 8) = o;
    }
    return;
  }
  bid -= J2_BLOCKS;
  {  // head H: single l2norm of xp; 4 rows per wave
    int base = bid * 16 + (threadIdx.x >> 6) * 4;
    int dd = threadIdx.x & 63;
    #pragma unroll
    for (int i = 0; i < 4; ++i) {
      int row = base + i;
      if (row >= B_DIM * TP1) break;
      int b = row / TP1, t = row - b * TP1;
      float v = (t < T_DIM) ? x[((size_t)b * T_DIM + t) * 64 + dd] : 0.0f;
      float ss = v * v;
      ss += __shfl_xor(ss, 1);  ss += __shfl_xor(ss, 2);
      ss += __shfl_xor(ss, 4);  ss += __shfl_xor(ss, 8);
      ss += __shfl_xor(ss, 16); ss += __shfl_xor(ss, 32);
      float inv = 1.0f / (sqrtf(ss) + EPS);
      __builtin_nontemporal_store(v * inv,
          &out[(((size_t)(H_DIM * B_DIM + b) * TP1 + t) << 6) + dd]);
    }
  }
}

// RESTORED BEST-MEASURED MM (R4 submission, total 101.118us): block =
// (h, b-pair, 128 rows), 4 waves: wm = w&1 owns a 64-row half
// (tw = t0 + 64*wm), wb = w>>1 owns one b; each wave does its full K.
// 3 LDS buffers (79.9KB), counted vmcnt (14/12 -> 7/6 -> 0, 2-3 stages in
// flight), 2 barriers/step, stage(it+3) after the read-completion barrier,
// A-frag dedup (6 entries). CU-balanced lvl bijection k<8?k:(k<16?23-k:16)
// pairs (k,15-k) -> 37-38 steps on every CU. h = bid&7 pins one head/XCD.
// 12-round verdict: MM is L2-latency-plateau-bound (~41us; MfmaUtil ~14%,
// VALU ~26%, HBM ~11%, nothing saturated); staged 41 < direct-to-reg 48 <
// R0 64; all schedule variants inside the staged skeleton are neutral.
__global__ __launch_bounds__(256) void toeplitz_mm(const unsigned short* __restrict__ fragA,
                                                   const unsigned short* __restrict__ xT,
                                                   float* __restrict__ out) {
  __shared__ __align__(16) char smem[3][BUFSZ];

  const int lane = threadIdx.x & 63;
  const int w    = threadIdx.x >> 6;
  const int wm   = w & 1;
  const int wb   = w >> 1;
  const int lm   = lane & 15;
  const int quad = lane >> 4;

  const int bid = blockIdx.x;
  const int h   = bid & 7;
  const int bg  = (bid >> 3) & 3;
  const int k   = bid >> 5;                 // 0..16
  const int lvl = (k < 8) ? k : ((k < 16) ? 23 - k : 16);  // CU-balanced pairing
  const int t0  = T_DIM - lvl * 128;
  const int tw  = t0 + 64 * wm;
  const int b   = bg * 2 + wb;
  const bool active = (tw <= T_DIM);
  const int cap = tw + 32;                  // last valid 32-chunk base for this wave

  const int NS = (min(t0 + 96, T_DIM) >> 6) + 1;   // always >= 2

  const unsigned short* fA = fragA + (size_t)h * NFRAG * 512 + lane * 8;

  // Stage step 'it' into smem[bufi]: units 0..9 = A entries E0p..E0p+9 (1KB each),
  // units 10..25 = B pieces (2 b's x 8 x 1KB). Unit u = w + 4*i: waves 0,1 issue
  // 7 loads; waves 2,3 issue 6 (used for the counted vmcnt below).
#define STAGE(bufi, it) do {                                                   \
    int _s0 = (it) << 6;                                                       \
    int _E0p = ((t0 - _s0 + 32) >> 4) + 6;                                     \
    const unsigned short* _A = fA + (size_t)_E0p * 512;                        \
    const unsigned short* _B = xT + ((size_t)((bg * 2) * NST + (_s0 >> 6)) << 12) + lane * 8; \
    char* _lb = &smem[bufi][0];                                                \
    _Pragma("unroll")                                                          \
    for (int _i = 0; _i < 7; ++_i) {                                           \
      int _u = w + _i * 4;                                                     \
      if (_u < 26) {                                                           \
        const unsigned short* _src = (_u < 10)                                 \
            ? (_A + (size_t)_u * 512)                                          \
            : (_B + (((_u - 10) >> 3) * (NST * 4096)) + (((_u - 10) & 7) * 512)); \
        load_lds16(_src, _lb + _u * 1024);                                     \
      }                                                                        \
    }                                                                          \
  } while (0)

  v4f acc[4][4] = {};  // rows tw+16*mt+4*quad+r, cols (b, 16*nt+lm)

  STAGE(0, 0);
  STAGE(1, 1);
  if (NS > 2) STAGE(2, 2);
  int it3 = 0;                               // it % 3
  for (int it = 0; it < NS; ++it) {
    // Wait until stage(it) has landed: allow (stages still in flight) to remain.
    int rem = NS - 1 - it; if (rem > 2) rem = 2;
    if (w < 2) {
      if (rem == 2)      asm volatile("s_waitcnt vmcnt(14)" ::: "memory");
      else if (rem == 1) asm volatile("s_waitcnt vmcnt(7)"  ::: "memory");
      else               asm volatile("s_waitcnt vmcnt(0)"  ::: "memory");
    } else {
      if (rem == 2)      asm volatile("s_waitcnt vmcnt(12)" ::: "memory");
      else if (rem == 1) asm volatile("s_waitcnt vmcnt(6)"  ::: "memory");
      else               asm volatile("s_waitcnt vmcnt(0)"  ::: "memory");
    }
    __builtin_amdgcn_s_barrier();            // everyone's stage(it) landed
    __builtin_amdgcn_sched_barrier(0);       // no ds_read hoists above this point

    const char* Ab = &smem[it3][0];
    const char* Bb = Ab + AREG + wb * 8192;
    int s0 = it << 6;
    __builtin_amdgcn_s_setprio(1);
    v8s af6[6];
    #pragma unroll
    for (int e = 0; e < 6; ++e)
      af6[e] = *(const v8s*)(Ab + (e + 4 * wm) * 1024 + lane * 16);
    #pragma unroll
    for (int kk = 0; kk < 2; ++kk) {
      if (active && (s0 + 32 * kk <= cap)) {
        v8s bf[4];
        #pragma unroll
        for (int nt = 0; nt < 4; ++nt)
          bf[nt] = *(const v8s*)(Bb + nt * 2048 + lm * 128 +
                                 ((((kk << 2) | quad) ^ (lm & 7)) << 4));
        #pragma unroll
        for (int mt = 0; mt < 4; ++mt)
          #pragma unroll
          for (int nt = 0; nt < 4; ++nt)
            acc[mt][nt] = __builtin_amdgcn_mfma_f32_16x16x32_bf16(
                af6[(kk ? 0 : 2) + mt], bf[nt], acc[mt][nt], 0, 0, 0);
      }
    }
    __builtin_amdgcn_s_setprio(0);
    __builtin_amdgcn_sched_barrier(0);
    __builtin_amdgcn_s_barrier();            // all waves done reading smem[it3]
    if (it + 3 < NS) STAGE(it3, it + 3);     // loads fly for TWO whole steps
    if (++it3 == 3) it3 = 0;
  }

  if (!active) return;

  // Epilogue: double l2-norm over dd (softmax Z cancels up to eps ~3e-7).
  // C/D layout: col = lane&15 (dd offset), row = quad*4 + reg.
  #pragma unroll
  for (int mt = 0; mt < 4; ++mt) {
    #pragma unroll
    for (int r = 0; r < 4; ++r) {
      float ss = 0.0f;
      #pragma unroll
      for (int nt = 0; nt < 4; ++nt) { float a = acc[mt][nt][r]; ss += a * a; }
      ss += __shfl_xor(ss, 1);
      ss += __shfl_xor(ss, 2);
      ss += __shfl_xor(ss, 4);
      ss += __shfl_xor(ss, 8);
      int t = tw + 16 * mt + 4 * quad + r;
      if (t <= T_DIM) {
        float n1 = sqrtf(ss);
        float u  = n1 / (n1 + EPS);
        float inv = 1.0f / ((n1 + EPS) * (u + EPS));
        float* op = out + (((size_t)(h * B_DIM + b) * TP1 + t) << 6) + lm;
        #pragma unroll
        for (int nt = 0; nt < 4; ++nt)
          __builtin_nontemporal_store(acc[mt][nt][r] * inv, op + 16 * nt);
      }
    }
  }
#undef STAGE
}

extern "C" void kernel_launch(void* const* d_in, const int* in_sizes, int n_in,
                              void* d_out, int out_size, void* d_ws, size_t ws_size,
                              hipStream_t stream) {
  const float* x = (const float*)d_in[0];   // [8, 2048, 64] fp32
  const float* W = (const float*)d_in[1];   // [2048, 8] fp32
  float* out = (float*)d_out;               // [9, 8, 2049, 64] fp32

  unsigned short* xT    = (unsigned short*)d_ws;                    // 8*33*8192 = 2,162,688 B
  unsigned short* fragA = (unsigned short*)((char*)d_ws + 2162688); // 8*146*1024 = 1,196,032 B

  hipLaunchKernelGGL(prep, dim3(J1_BLOCKS + J2_BLOCKS + J3_BLOCKS), dim3(256), 0, stream,
                     x, W, fragA, xT, out);
  hipLaunchKernelGGL(toeplitz_mm, dim3(MM_BLOCKS), dim3(256), 0, stream,
                     fragA, xT, out);
}